// Round 6
// baseline (45.002 us; speedup 1.0000x reference)
//
#include <hip/hip_runtime.h>
#include <math.h>

// TripletLoss: B=16384 rows, D=1024 fp32.
// dp=||a-p||, dn=||a-n||, loss=softplus(dp-dn), out = mean(loss).
// Memory-bound: 192 MiB read once -> ~33us main loop at ~6.1 TB/s (fabric
// ceiling; half the reads are L3 hits but the cap applies to the blend).
//
// Epilogue lessons (harness graph timing):
//   R1: two kernels                          -> 36.7us (+~4 second dispatch)
//   R2: 2048x __threadfence                  -> 105us  (L2 writeback poison)
//   R3: 2048x atomicAdd on ONE address       -> 54us   (~8ns x 2048 convoy)
//   R4: payload spread, ticket on one addr   -> 54us   (convoy just moved)
//   R5: 2048 blocks, 64+64 RMWs per line     -> 42us   (line convoy + chains)
// R6: 512 blocks x 1024 threads (same 8192 waves, same main loop). In-block
//     LDS reduce over 16 waves first -> only 512 global payload RMWs
//     (16/line over 32 lines), 512 local tickets, 32 leaders -> 1 global.
//     Hottest line: 32 RMWs. No __threadfence anywhere.

#define B_ROWS 16384
#define D_DIM  1024
#define NBLOCKS 512
#define NTHREADS 1024
#define NWAVES (NTHREADS / 64)    // 16 waves/block
#define NSLOTS 32
#define SLOT_STRIDE 64            // floats: 256B between slot lines
#define BLOCKS_PER_SLOT (NBLOCKS / NSLOTS)   // 16

__global__ __launch_bounds__(NTHREADS) void triplet_hier2_kernel(
    const float* __restrict__ a,
    const float* __restrict__ p,
    const float* __restrict__ n,
    float* __restrict__ slots,          // 32 lines: [0]=sum, [1]=local ticket
    unsigned int* __restrict__ gcnt,    // global ticket (leaders only)
    float* __restrict__ out)
{
    const int wave = threadIdx.x >> 6;   // 0..15
    const int lane = threadIdx.x & 63;
    const int globalWave = blockIdx.x * NWAVES + wave;   // 0..8191
    const int totalWaves = gridDim.x * NWAVES;           // 8192

    float acc = 0.0f;  // per-wave loss accumulator (lane 0 only meaningful)

    for (int row = globalWave; row < B_ROWS; row += totalWaves) {
        const float4* a4 = (const float4*)(a + (size_t)row * D_DIM);
        const float4* p4 = (const float4*)(p + (size_t)row * D_DIM);
        const float4* n4 = (const float4*)(n + (size_t)row * D_DIM);
        float sp = 0.0f, sn = 0.0f;
        #pragma unroll
        for (int k = 0; k < 4; ++k) {
            const int idx = lane + 64 * k;   // coalesced: 64 lanes x 16B contiguous
            float4 av = a4[idx];
            float4 pv = p4[idx];
            float4 nv = n4[idx];
            float d0 = av.x - pv.x, d1 = av.y - pv.y,
                  d2 = av.z - pv.z, d3 = av.w - pv.w;
            sp += d0*d0 + d1*d1 + d2*d2 + d3*d3;
            d0 = av.x - nv.x; d1 = av.y - nv.y;
            d2 = av.z - nv.z; d3 = av.w - nv.w;
            sn += d0*d0 + d1*d1 + d2*d2 + d3*d3;
        }
        // 64-lane butterfly reduce (wave = 64 on CDNA)
        #pragma unroll
        for (int off = 32; off > 0; off >>= 1) {
            sp += __shfl_xor(sp, off, 64);
            sn += __shfl_xor(sn, off, 64);
        }
        if (lane == 0) {
            float dp = sqrtf(sp);
            float dn = sqrtf(sn);
            float x  = dp - dn;
            // stable softplus: logaddexp(0,x) = max(x,0) + log1p(exp(-|x|))
            acc += fmaxf(x, 0.0f) + log1pf(expf(-fabsf(x)));
        }
    }

    __shared__ float smem[NWAVES];
    if (lane == 0) smem[wave] = acc;
    __syncthreads();

    __shared__ int s_final;
    if (threadIdx.x == 0) {
        s_final = 0;
        float block_sum = 0.0f;
        #pragma unroll
        for (int i = 0; i < NWAVES; ++i) block_sum += smem[i];

        float* slot = slots + (blockIdx.x & (NSLOTS - 1)) * SLOT_STRIDE;

        // Payload: 16-way convoy per line, 32 lines in parallel.
        float old = atomicAdd(slot, block_sum);
        asm volatile("" :: "v"(old));                     // keep RMW result live
        asm volatile("s_waitcnt vmcnt(0)" ::: "memory");  // payload at coherence pt

        unsigned lt = atomicAdd((unsigned int*)(slot + 1), 1u);
        if (lt == (unsigned)(BLOCKS_PER_SLOT - 1)) {
            // Group leader: my line's 16 payloads are complete.
            asm volatile("s_waitcnt vmcnt(0)" ::: "memory");
            unsigned gt = atomicAdd(gcnt, 1u);            // 32-way convoy
            if (gt == (unsigned)(NSLOTS - 1)) s_final = 1;
        }
    }
    __syncthreads();

    if (s_final) {
        // Last leader: all 512 payloads complete. RMW-read the 32 sums
        // (coherence-point reads, parallel across lines).
        float v = 0.0f;
        if (threadIdx.x < NSLOTS)
            v = atomicAdd(&slots[threadIdx.x * SLOT_STRIDE], 0.0f);
        #pragma unroll
        for (int off = 32; off > 0; off >>= 1)
            v += __shfl_xor(v, off, 64);
        if (threadIdx.x == 0)
            out[0] = v * (1.0f / (float)B_ROWS);
    }
}

extern "C" void kernel_launch(void* const* d_in, const int* in_sizes, int n_in,
                              void* d_out, int out_size, void* d_ws, size_t ws_size,
                              hipStream_t stream) {
    const float* anchor   = (const float*)d_in[0];
    const float* positive = (const float*)d_in[1];
    const float* negative = (const float*)d_in[2];
    float* out = (float*)d_out;
    float* slots = (float*)d_ws;                               // 32 x 256B = 8192 B
    unsigned int* gcnt = (unsigned int*)((char*)d_ws + NSLOTS * SLOT_STRIDE * sizeof(float));

    // Slots (sum + local tickets) and global ticket must be zero each call
    // (ws poisoned 0xAA once, never re-poisoned). One async memset node.
    hipMemsetAsync(d_ws, 0,
                   NSLOTS * SLOT_STRIDE * sizeof(float) + sizeof(unsigned int),
                   stream);

    triplet_hier2_kernel<<<NBLOCKS, NTHREADS, 0, stream>>>(anchor, positive, negative,
                                                           slots, gcnt, out);
}

// Round 7
// 35.335 us; speedup vs baseline: 1.2736x; 1.2736x over previous
//
#include <hip/hip_runtime.h>
#include <math.h>

// TripletLoss: B=16384 rows, D=1024 fp32.
// dp=||a-p||, dn=||a-n||, loss=softplus(dp-dn), out = mean(loss).
//
// Memory-bound: 201.3 MB read once. Floor = 201.3MB / 6.29 TB/s (m13 copy
// ceiling) = 32.0us. Main loop measures ~33.5us (~95% of ceiling).
//
// Structure ladder (harness graph timing):
//   R1: two kernels (this structure)        -> 36.7us   <- BEST
//   R2: fused, 2048x __threadfence          -> 105us  (L2 writeback poison)
//   R3: fused, 2048x atomicAdd one addr     -> 54us   (~8ns x 2048 RMW convoy)
//   R4: fused, spread payload, one ticket   -> 54us   (convoy moved to ticket)
//   R5: fused, hierarchical 64/line         -> 42us   (memset node ~3.5 + epi ~5)
//   R6: R5 with 1024-thread blocks          -> 45us   (fat blocks slow main loop)
// Conclusion: any fused cross-XCD completion protocol costs more than the
// plain second dispatch (~3.2us). Keep two kernels.

#define B_ROWS 16384
#define D_DIM  1024
#define NBLOCKS 2048   // 4 waves/block -> 8192 waves, 2 rows per wave

__global__ __launch_bounds__(256) void triplet_partial_kernel(
    const float* __restrict__ a,
    const float* __restrict__ p,
    const float* __restrict__ n,
    float* __restrict__ partial)
{
    const int wave = threadIdx.x >> 6;   // 0..3
    const int lane = threadIdx.x & 63;
    const int globalWave = blockIdx.x * 4 + wave;
    const int totalWaves = gridDim.x * 4;

    float acc = 0.0f;  // per-wave loss accumulator (lane 0 only meaningful)

    for (int row = globalWave; row < B_ROWS; row += totalWaves) {
        const float4* a4 = (const float4*)(a + (size_t)row * D_DIM);
        const float4* p4 = (const float4*)(p + (size_t)row * D_DIM);
        const float4* n4 = (const float4*)(n + (size_t)row * D_DIM);
        float sp = 0.0f, sn = 0.0f;
        #pragma unroll
        for (int k = 0; k < 4; ++k) {
            const int idx = lane + 64 * k;   // coalesced: 64 lanes x 16B contiguous
            float4 av = a4[idx];
            float4 pv = p4[idx];
            float4 nv = n4[idx];
            float d0 = av.x - pv.x, d1 = av.y - pv.y,
                  d2 = av.z - pv.z, d3 = av.w - pv.w;
            sp += d0*d0 + d1*d1 + d2*d2 + d3*d3;
            d0 = av.x - nv.x; d1 = av.y - nv.y;
            d2 = av.z - nv.z; d3 = av.w - nv.w;
            sn += d0*d0 + d1*d1 + d2*d2 + d3*d3;
        }
        // 64-lane butterfly reduce (wave = 64 on CDNA)
        #pragma unroll
        for (int off = 32; off > 0; off >>= 1) {
            sp += __shfl_xor(sp, off, 64);
            sn += __shfl_xor(sn, off, 64);
        }
        if (lane == 0) {
            float dp = sqrtf(sp);
            float dn = sqrtf(sn);
            float x  = dp - dn;
            // stable softplus: logaddexp(0,x) = max(x,0) + log1p(exp(-|x|))
            acc += fmaxf(x, 0.0f) + log1pf(expf(-fabsf(x)));
        }
    }

    __shared__ float smem[4];
    if (lane == 0) smem[wave] = acc;
    __syncthreads();
    if (threadIdx.x == 0)
        partial[blockIdx.x] = smem[0] + smem[1] + smem[2] + smem[3];
}

__global__ __launch_bounds__(256) void triplet_final_kernel(
    const float* __restrict__ partial, float* __restrict__ out)
{
    const int wave = threadIdx.x >> 6;
    const int lane = threadIdx.x & 63;
    // 2048 floats = 512 float4; 256 threads x 2 float4 each, coalesced.
    const float4* p4 = (const float4*)partial;
    float acc = 0.0f;
    #pragma unroll
    for (int k = 0; k < 2; ++k) {
        float4 v = p4[threadIdx.x + 256 * k];
        acc += v.x + v.y + v.z + v.w;
    }
    #pragma unroll
    for (int off = 32; off > 0; off >>= 1) acc += __shfl_xor(acc, off, 64);
    __shared__ float smem[4];
    if (lane == 0) smem[wave] = acc;
    __syncthreads();
    if (threadIdx.x == 0)
        out[0] = (smem[0] + smem[1] + smem[2] + smem[3]) * (1.0f / (float)B_ROWS);
}

extern "C" void kernel_launch(void* const* d_in, const int* in_sizes, int n_in,
                              void* d_out, int out_size, void* d_ws, size_t ws_size,
                              hipStream_t stream) {
    const float* anchor   = (const float*)d_in[0];
    const float* positive = (const float*)d_in[1];
    const float* negative = (const float*)d_in[2];
    float* out = (float*)d_out;
    float* partials = (float*)d_ws;   // NBLOCKS floats = 8 KB scratch

    triplet_partial_kernel<<<NBLOCKS, 256, 0, stream>>>(anchor, positive, negative, partials);
    triplet_final_kernel<<<1, 256, 0, stream>>>(partials, out);
}